// Round 11
// baseline (607.956 us; speedup 1.0000x reference)
//
#include <hip/hip_runtime.h>
#include <math.h>

constexpr int N_ = 32, C_ = 512, T_ = 1024;
constexpr int NTOK = N_ * T_;      // 32768
constexpr int NCODE = 2048;
constexpr int K = 512;

#define MUF 0.99f
#define OMM 0.01f

// Output layout (flat f32, return order)
constexpr long long OFF_XD   = 0;
constexpr long long OFF_LOSS = 16777216;
constexpr long long OFF_PERP = 16777217;
constexpr long long OFF_CB   = 16777218;                           // new_codebook (2048,512)
constexpr long long OFF_CSUM = OFF_CB  + (long long)NCODE * C_;
constexpr long long OFF_CCNT = OFF_CSUM + (long long)NCODE * C_;

// CB-region scratch (floats from OFF_CB; overwritten by k_update_cb last)
constexpr long long S_IDX  = OFF_CB;             // int[32768]
constexpr long long S_NRM  = OFF_CB + 32768;     // float[2048] half-norms
constexpr long long S_CNT  = OFF_CB + 34816;     // int[2048]
constexpr long long S_BASE = OFF_CB + 36864;     // int[2048]
constexpr long long S_CUR  = OFF_CB + 38912;     // int[2048]
constexpr long long S_TOK  = OFF_CB + 40960;     // int[32768]
constexpr long long S_PBD  = OFF_CB + 73728;     // float[4][32768]
constexpr long long S_PBJ  = OFF_CB + 335872;    // int[4][32768]
//
// PANEL layouts (HW-verified round 6/8/9): every staged row is a full aligned 128-B line
// holding hi(64 B)+lo(64 B) of one row's 32-wide K-slice:
//   X panels (XD region, byte 0): XP(p,tok) = (p*NTOK + tok)*64 ushorts (p = kc/32)
//   CB panels (CSUM region + 120 B, 128-B aligned): CP(p,j) = (p*NCODE + j)*64; 120-B
//     tail spills into OFF_CCNT, which k_scan overwrites AFTER argmin — safe.
// Both dead after argmin: CSUM region becomes the f32 new_code_sum atomicAdd target,
// XD region overwritten by k_xd.
//
// COMMIT LOSS via norm identity (round 11): sum||x-c||^2 = sum(x^2) + 2*sum_t(bd_t)
// where bd = 0.5||c||^2 - x.c is argmin's winning value. sum(x^2) accumulated by
// k_transpose (one atomic per wave); 2*sum(bd) by k_merge. k_xd is a pure gather
// (x + (cb - x) == cb[idx]) — no x read.

typedef __bf16 bf16x8 __attribute__((ext_vector_type(8)));
typedef float f32x4 __attribute__((ext_vector_type(4)));

__device__ inline unsigned short f2bf(float f) {
    unsigned int u = __float_as_uint(f);
    unsigned int r = u + 0x7fffu + ((u >> 16) & 1u);
    return (unsigned short)(r >> 16);
}
__device__ inline float bf2f(unsigned short h) {
    return __uint_as_float(((unsigned int)h) << 16);
}

// direct global->LDS async copy, 16 B per lane (global_load_lds_dwordx4)
__device__ inline void gld16(const unsigned short* g, unsigned short* l) {
    __builtin_amdgcn_global_load_lds(
        (const __attribute__((address_space(1))) unsigned int*)g,
        (__attribute__((address_space(3))) unsigned int*)l,
        16, 0, 0);
}

// ---------------------------------------------- prep: cb -> CB panels + half-norms + zeros
__global__ void k_prep_cb(const float* __restrict__ cb, float* __restrict__ out) {
    int j = blockIdx.x, l = threadIdx.x;          // 2048 x 64 ; cols l*8..l*8+7
    unsigned short* cp = (unsigned short*)(out + OFF_CSUM) + 60;   // 128-B aligned
    const float* row = cb + (long long)j * K;
    float4 a = *(const float4*)(row + l * 8);
    float4 b = *(const float4*)(row + l * 8 + 4);
    float v[8] = {a.x, a.y, a.z, a.w, b.x, b.y, b.z, b.w};
    unsigned short h[8], lo[8];
    float s = 0.0f;
    #pragma unroll
    for (int k = 0; k < 8; ++k) {
        s += v[k] * v[k];
        h[k] = f2bf(v[k]);
        lo[k] = f2bf(v[k] - bf2f(h[k]));
    }
    const int p = l >> 2, cw = (l & 3) * 8;       // kstep, in-panel col
    const long long base = ((long long)p * NCODE + j) * 64;
    *(uint4*)&cp[base + cw]      = *(uint4*)h;
    *(uint4*)&cp[base + 32 + cw] = *(uint4*)lo;
    #pragma unroll
    for (int off = 32; off >= 1; off >>= 1) s += __shfl_down(s, off, 64);
    if (l == 0) out[S_NRM + j] = 0.5f * s;
    if (l == 1) ((int*)(out + S_CNT))[j] = 0;
    if (j == 0 && l == 2) out[OFF_LOSS] = 0.0f;
}

// ---------------------------------------------- transpose x -> X panels (+ sum x^2 -> LOSS)
__global__ void k_transpose(const float* __restrict__ x, float* __restrict__ out) {
    __shared__ unsigned int tile[64][65];
    unsigned short* xp = (unsigned short*)out;
    const int t0 = blockIdx.x * 64, c0 = blockIdx.y * 64, n = blockIdx.z;
    const int tid = threadIdx.x;
    float s2 = 0.0f;
    #pragma unroll
    for (int i = 0; i < 4; ++i) {
        int s = tid + 256 * i;
        int cl = s >> 4, tq = (s & 15) * 4;
        float4 v = *(const float4*)(x + ((long long)(n * C_ + c0 + cl)) * T_ + t0 + tq);
        float vv[4] = {v.x, v.y, v.z, v.w};
        #pragma unroll
        for (int k = 0; k < 4; ++k) {
            s2 += vv[k] * vv[k];
            unsigned short h = f2bf(vv[k]);
            unsigned short lo = f2bf(vv[k] - bf2f(h));
            tile[cl][tq + k] = ((unsigned int)h << 16) | lo;
        }
    }
    #pragma unroll
    for (int off = 32; off >= 1; off >>= 1) s2 += __shfl_down(s2, off, 64);
    if ((tid & 63) == 0) atomicAdd(&out[OFF_LOSS], s2);
    __syncthreads();
    #pragma unroll
    for (int i = 0; i < 4; ++i) {
        int s = tid + 256 * i;
        int tr = s >> 4, cq = (s & 15) * 4;
        unsigned short h4[4], l4[4];
        #pragma unroll
        for (int k = 0; k < 4; ++k) {
            unsigned int u = tile[cq + k][tr];
            h4[k] = (unsigned short)(u >> 16);
            l4[k] = (unsigned short)(u & 0xffff);
        }
        long long tok = (long long)n * T_ + t0 + tr;
        int cg = c0 + cq;
        int p = cg >> 5, cw = cg & 31;
        long long base = ((long long)p * NTOK + tok) * 64;
        *(uint2*)&xp[base + cw]      = *(uint2*)h4;
        *(uint2*)&xp[base + 32 + cw] = *(uint2*)l4;
    }
}

// ---------------------------------------------- MFMA argmin: 128 tok x 1024 codes per block
// grid 512 (bijective XCD swizzle; exactly one residency round at 2 blocks/CU). 4 waves;
// wave tile 64x128: moff=(w>>1)*64, noff=(w&1)*128. jt=0..3 covers 256 codes each.
// Partial group g = jn*2 + (w&1), 4 groups. Inner body IDENTICAL to round 8 (verified
// 180 us, MfmaUtil 51.5, WRITE 2 MB): A+B staged via gld16 w16 panels, XOR involution,
// 2 barriers/step. jn-merge halves A re-fetch (273 -> ~150 MB) and removes the second
// dispatch round's prologue/drain tail. R9 (counted vmcnt) and R10 (full dbuf, 32x128
// tile) both failed to beat this structure — the ~3000 cyc/step residual is LDS-read
// serialization + barrier skew, untouched by load-latency scheduling.
__global__ __launch_bounds__(256, 2)
void k_argmin(const float* __restrict__ out_ro, float* __restrict__ out) {
    extern __shared__ unsigned short sm[];
    unsigned short* As = sm;            // [128 rows][128 B] = 16 KB
    unsigned short* Bs = sm + 8192;     // [256 rows][128 B] = 32 KB
    const unsigned short* xp = (const unsigned short*)out_ro;
    const unsigned short* cp = (const unsigned short*)(out_ro + OFF_CSUM) + 60;
    const float* nrm = out_ro + S_NRM;

    const int tid = threadIdx.x;
    const int bid = blockIdx.x;
    const int sw  = (bid & 7) * 64 + (bid >> 3);   // bijective (512 % 8 == 0)
    const int jn  = sw >> 8;                        // code group (1024): 0 or 1
    const int it  = sw & 255;                       // token tile (128)
    const int w = tid >> 6, L = tid & 63;
    const int quad = L >> 4, l16 = L & 15;
    const int moff = (w >> 1) * 64, noff = (w & 1) * 128;

    // staging: dest chunk linear (sA + i*2048); source row rA + i*32 with i-independent
    // chunk involution ku8; fragment read phys chunk = quad ^ (row&7), lo = hi ^ 32.
    const int sA = tid * 8;
    const int rA = tid >> 3;
    const int ku8 = ((tid & 7) ^ (rA & 7)) * 8;
    const int fhi = (quad ^ (l16 & 7)) << 3;

    float bd[4][4];
    int   bj[4][4];
    #pragma unroll
    for (int mt = 0; mt < 4; ++mt)
        #pragma unroll
        for (int r = 0; r < 4; ++r) { bd[mt][r] = 3.4e38f; bj[mt][r] = 0; }

    for (int jt = 0; jt < 4; ++jt) {
        const int jbase = jn * 1024 + jt * 256;
        f32x4 acc[4][8];
        #pragma unroll
        for (int mt = 0; mt < 4; ++mt)
            #pragma unroll
            for (int nt = 0; nt < 8; ++nt) acc[mt][nt] = (f32x4)(0.0f);

        for (int p = 0; p < 16; ++p) {                 // kc = p*32
            __syncthreads();
            const long long ab = ((long long)p * NTOK + it * 128 + rA) * 64 + ku8;
            const long long bb = ((long long)p * NCODE + jbase + rA) * 64 + ku8;
            #pragma unroll
            for (int i = 0; i < 4; ++i)
                gld16(xp + ab + i * 2048, As + sA + i * 2048);
            #pragma unroll
            for (int i = 0; i < 8; ++i)
                gld16(cp + bb + i * 2048, Bs + sA + i * 2048);
            __syncthreads();   // drains vmcnt before any wave reads the tiles
            bf16x8 ah[4], al[4];
            #pragma unroll
            for (int mt = 0; mt < 4; ++mt) {
                int oa = (moff + mt * 16 + l16) * 64 + fhi;
                ah[mt] = *(const bf16x8*)&As[oa];
                al[mt] = *(const bf16x8*)&As[oa ^ 32];
            }
            #pragma unroll
            for (int nt = 0; nt < 8; ++nt) {
                int ob = (noff + nt * 16 + l16) * 64 + fhi;
                bf16x8 bh = *(const bf16x8*)&Bs[ob];
                bf16x8 bl = *(const bf16x8*)&Bs[ob ^ 32];
                #pragma unroll
                for (int mt = 0; mt < 4; ++mt)
                    acc[mt][nt] = __builtin_amdgcn_mfma_f32_16x16x32_bf16(ah[mt], bh, acc[mt][nt], 0, 0, 0);
                #pragma unroll
                for (int mt = 0; mt < 4; ++mt)
                    acc[mt][nt] = __builtin_amdgcn_mfma_f32_16x16x32_bf16(al[mt], bh, acc[mt][nt], 0, 0, 0);
                #pragma unroll
                for (int mt = 0; mt < 4; ++mt)
                    acc[mt][nt] = __builtin_amdgcn_mfma_f32_16x16x32_bf16(ah[mt], bl, acc[mt][nt], 0, 0, 0);
                __builtin_amdgcn_sched_barrier(0);     // pin bh/bl live range (reg cap)
            }
        }
        // epilogue: fold this 128x256 tile into running per-token best
        #pragma unroll
        for (int nt = 0; nt < 8; ++nt) {
            int n = jbase + noff + nt * 16 + l16;
            float nv = nrm[n];
            #pragma unroll
            for (int mt = 0; mt < 4; ++mt)
                #pragma unroll
                for (int r = 0; r < 4; ++r) {
                    float d = nv - acc[mt][nt][r];
                    if (d < bd[mt][r]) { bd[mt][r] = d; bj[mt][r] = n; }
                }
        }
    }

    // cross-lane reduce over the 16 lanes of each quad (xor masks 1,2,4,8)
    #pragma unroll
    for (int off = 1; off < 16; off <<= 1) {
        #pragma unroll
        for (int mt = 0; mt < 4; ++mt)
            #pragma unroll
            for (int r = 0; r < 4; ++r) {
                float od = __shfl_xor(bd[mt][r], off, 64);
                int   oj = __shfl_xor(bj[mt][r], off, 64);
                if (od < bd[mt][r] || (od == bd[mt][r] && oj < bj[mt][r])) {
                    bd[mt][r] = od; bj[mt][r] = oj;
                }
            }
    }
    if (l16 == 0) {
        int g = jn * 2 + (w & 1);
        float* pbd = out + S_PBD + (long long)g * NTOK;
        int*   pbj = (int*)(out + S_PBJ) + (long long)g * NTOK;
        #pragma unroll
        for (int mt = 0; mt < 4; ++mt)
            #pragma unroll
            for (int r = 0; r < 4; ++r) {
                int tok = it * 128 + moff + mt * 16 + quad * 4 + r;
                pbd[tok] = bd[mt][r];
                pbj[tok] = bj[mt][r];
            }
    }
}

// ---------------------------------------------- merge 4 partials -> idx + hist + loss(2*bd)
__global__ void k_merge(const float* __restrict__ out_ro, int* __restrict__ idx,
                        int* __restrict__ cnt, float* __restrict__ out) {
    int t = blockIdx.x * 256 + threadIdx.x;
    const float* pbd = out_ro + S_PBD;
    const int*   pbj = (const int*)(out_ro + S_PBJ);
    float bd = 3.4e38f; int bj = 0;
    #pragma unroll
    for (int g = 0; g < 4; ++g) {
        float d = pbd[(long long)g * NTOK + t];
        int   j = pbj[(long long)g * NTOK + t];
        if (d < bd || (d == bd && j < bj)) { bd = d; bj = j; }
    }
    idx[t] = bj;
    atomicAdd(&cnt[bj], 1);
    // commit-loss partial: sum_t 2*bd_t (norm identity; x^2 term added by k_transpose)
    float ls = 2.0f * bd;
    #pragma unroll
    for (int off = 32; off >= 1; off >>= 1) ls += __shfl_down(ls, off, 64);
    if ((threadIdx.x & 63) == 0) atomicAdd(&out[OFF_LOSS], ls);
}

__global__ void k_scan(const int* __restrict__ cnt, int* __restrict__ base,
                       int* __restrict__ cursor, const float* __restrict__ code_count,
                       float* __restrict__ out) {
    __shared__ int ps[256];
    __shared__ float hs[256];
    int tid = threadIdx.x;
    int local[8]; int s = 0;
    #pragma unroll
    for (int q = 0; q < 8; ++q) { local[q] = cnt[tid * 8 + q]; s += local[q]; }
    ps[tid] = s; __syncthreads();
    for (int st = 1; st < 256; st <<= 1) {
        int v = (tid >= st) ? ps[tid - st] : 0;
        __syncthreads();
        ps[tid] += v;
        __syncthreads();
    }
    int b = ps[tid] - s;
    float h = 0.0f;
    #pragma unroll
    for (int q = 0; q < 8; ++q) {
        int j = tid * 8 + q;
        base[j] = b; cursor[j] = b; b += local[q];
        float p = (float)local[q] * (1.0f / 32768.0f);
        h += p * logf(p + 1e-7f);
        out[OFF_CCNT + j] = MUF * code_count[j] + OMM * (float)local[q];
    }
    hs[tid] = h; __syncthreads();
    for (int st = 128; st > 0; st >>= 1) {
        if (tid < st) hs[tid] += hs[tid + st];
        __syncthreads();
    }
    if (tid == 0) out[OFF_PERP] = expf(-hs[0]);
}

__global__ void k_place(const int* __restrict__ idx, int* __restrict__ cursor,
                        int* __restrict__ toklist) {
    int t = blockIdx.x * 256 + threadIdx.x;
    int pos = atomicAdd(&cursor[idx[t]], 1);
    toklist[pos] = t;
}

// ---------------------------------------------- segmented chunk scatter: raw new_code_sum
// 2048 blocks x 64 threads; block c handles sorted-token positions [c*16, c*16+16).
// Serial length is a fixed 16 regardless of per-code count skew. Flush is wave-uniform.
// Reads token rows from the X panels: lane l covers cols l*8..l*8+7 -> panel l>>2.
__global__ void k_chunksum(const int* __restrict__ toklist, const int* __restrict__ idx,
                           float* __restrict__ out) {
    const int c = blockIdx.x;
    const int l = threadIdx.x;
    const unsigned short* xp = (const unsigned short*)out;
    float* csum = out + OFF_CSUM;
    const int p0 = c * 16;
    const int pp = l >> 2, cw = (l & 3) * 8;
    float acc[8];
    #pragma unroll
    for (int q = 0; q < 8; ++q) acc[q] = 0.0f;
    int jcur = idx[toklist[p0]];
    #pragma unroll
    for (int i = 0; i < 16; ++i) {
        int tok = toklist[p0 + i];
        int j = idx[tok];
        if (j != jcur) {                                  // uniform across the wave
            #pragma unroll
            for (int q = 0; q < 8; ++q) {
                atomicAdd(&csum[(long long)jcur * C_ + l * 8 + q], acc[q]);
                acc[q] = 0.0f;
            }
            jcur = j;
        }
        long long base = ((long long)pp * NTOK + tok) * 64;
        uint4 hv = *(const uint4*)&xp[base + cw];
        uint4 lv = *(const uint4*)&xp[base + 32 + cw];
        unsigned int hu[4] = {hv.x, hv.y, hv.z, hv.w};
        unsigned int lu[4] = {lv.x, lv.y, lv.z, lv.w};
        #pragma unroll
        for (int q = 0; q < 4; ++q) {
            acc[q * 2 + 0] += bf2f((unsigned short)(hu[q] & 0xffff)) + bf2f((unsigned short)(lu[q] & 0xffff));
            acc[q * 2 + 1] += bf2f((unsigned short)(hu[q] >> 16))    + bf2f((unsigned short)(lu[q] >> 16));
        }
    }
    #pragma unroll
    for (int q = 0; q < 8; ++q)
        atomicAdd(&csum[(long long)jcur * C_ + l * 8 + q], acc[q]);
}

// ---------------------------------------------- x_d_out: pure codebook gather (overwrites X panels)
// x + (cb - x) == cb[idx]; loss handled by the norm identity (transpose + merge).
__global__ void k_xd(const float* __restrict__ cb, const int* __restrict__ idx,
                     float* __restrict__ out) {
    const int t = blockIdx.x * 256 + threadIdx.x;  // grid (4,4,32)
    const int c0 = blockIdx.y * 128;
    const int n = blockIdx.z;
    const int j = idx[n * T_ + t];
    const float4* cr = (const float4*)(cb + (long long)j * C_ + c0);
    const long long base = (long long)n * C_ * T_ + t;
    for (int c4 = 0; c4 < 32; ++c4) {
        float4 cv = cr[c4];
        float cvv[4] = {cv.x, cv.y, cv.z, cv.w};
        #pragma unroll
        for (int k = 0; k < 4; ++k) {
            int ci = c4 * 4 + k;
            out[OFF_XD + base + (long long)(c0 + ci) * T_] = cvv[k];
        }
    }
}

// ---------------------------------------------- codebook update/reset + CSUM EMA finalize + loss scale
__global__ void k_update_cb(const float* __restrict__ x, const float* __restrict__ code_sum,
                            float* __restrict__ out) {
    int e = blockIdx.x * 256 + threadIdx.x;   // 4096 blocks
    int j = e >> 9, c = e & 511;
    float cema = out[OFF_CCNT + j];
    float se = MUF * code_sum[e] + OMM * out[OFF_CSUM + e];   // raw acc -> EMA
    out[OFF_CSUM + e] = se;
    float val;
    if (cema >= 1.0f) val = se / fmaxf(cema, 1e-10f);
    else val = x[(long long)(j >> 10) * C_ * T_ + (long long)c * T_ + (j & 1023)];
    out[OFF_CB + e] = val;
    if (e == 0) out[OFF_LOSS] *= (1.0f / 16777216.0f);
}

// ---------------------------------------------- launch
extern "C" void kernel_launch(void* const* d_in, const int* in_sizes, int n_in,
                              void* d_out, int out_size, void* d_ws, size_t ws_size,
                              hipStream_t stream) {
    const float* x          = (const float*)d_in[0];
    const float* codebook   = (const float*)d_in[1];
    const float* code_sum   = (const float*)d_in[2];
    const float* code_count = (const float*)d_in[3];
    float* out = (float*)d_out;
    int*   idx     = (int*)(out + S_IDX);
    int*   cnt     = (int*)(out + S_CNT);
    int*   base    = (int*)(out + S_BASE);
    int*   cursor  = (int*)(out + S_CUR);
    int*   toklist = (int*)(out + S_TOK);

    constexpr int SMEM_ARGMIN = 49152;   // A 16 KB + B 32 KB; 2 blocks/CU
    hipFuncSetAttribute((const void*)k_argmin,
                        hipFuncAttributeMaxDynamicSharedMemorySize, SMEM_ARGMIN);

    k_prep_cb  <<<NCODE, 64, 0, stream>>>(codebook, out);
    dim3 gt(16, 8, 32);
    k_transpose<<<gt, 256, 0, stream>>>(x, out);
    k_argmin   <<<512, 256, SMEM_ARGMIN, stream>>>(out, out);
    k_merge    <<<128, 256, 0, stream>>>(out, idx, cnt, out);
    k_scan     <<<1, 256, 0, stream>>>(cnt, base, cursor, code_count, out);
    k_place    <<<128, 256, 0, stream>>>(idx, cursor, toklist);
    hipMemsetAsync(out + OFF_CSUM, 0, (size_t)NCODE * C_ * sizeof(float), stream);
    k_chunksum <<<2048, 64, 0, stream>>>(toklist, idx, out);
    dim3 gx(4, 4, 32);
    k_xd       <<<gx, 256, 0, stream>>>(codebook, idx, out);
    k_update_cb<<<4096, 256, 0, stream>>>(x, code_sum, out);
}

// Round 12
// 435.107 us; speedup vs baseline: 1.3973x; 1.3973x over previous
//
#include <hip/hip_runtime.h>
#include <math.h>

constexpr int N_ = 32, C_ = 512, T_ = 1024;
constexpr int NTOK = N_ * T_;      // 32768
constexpr int NCODE = 2048;
constexpr int K = 512;

#define MUF 0.99f
#define OMM 0.01f

// Output layout (flat f32, return order)
constexpr long long OFF_XD   = 0;
constexpr long long OFF_LOSS = 16777216;
constexpr long long OFF_PERP = 16777217;
constexpr long long OFF_CB   = 16777218;                           // new_codebook (2048,512)
constexpr long long OFF_CSUM = OFF_CB  + (long long)NCODE * C_;
constexpr long long OFF_CCNT = OFF_CSUM + (long long)NCODE * C_;

// CB-region scratch (floats from OFF_CB; overwritten by k_update_cb last)
constexpr long long S_IDX  = OFF_CB;             // int[32768]
constexpr long long S_NRM  = OFF_CB + 32768;     // float[2048] half-norms
constexpr long long S_CNT  = OFF_CB + 34816;     // int[2048]
constexpr long long S_BASE = OFF_CB + 36864;     // int[2048]
constexpr long long S_CUR  = OFF_CB + 38912;     // int[2048]
constexpr long long S_TOK  = OFF_CB + 40960;     // int[32768]
constexpr long long S_PBD  = OFF_CB + 73728;     // float[8][32768]
constexpr long long S_PBJ  = OFF_CB + 335872;    // int[8][32768]
//
// PANEL layouts (HW-verified round 6/8/9): every staged row is a full aligned 128-B line
// holding hi(64 B)+lo(64 B) of one row's 32-wide K-slice:
//   X panels (XD region, byte 0): XP(p,tok) = (p*NTOK + tok)*64 ushorts (p = kc/32)
//     line: ushorts [0..31] = hi of channels p*32..p*32+31, [32..63] = lo of same.
//   CB panels (CSUM region + 120 B, 128-B aligned): CP(p,j) = (p*NCODE + j)*64; 120-B
//     tail spills into OFF_CCNT, which k_scan overwrites AFTER argmin — safe.
// Both dead after argmin: CSUM region becomes the f32 new_code_sum atomicAdd target,
// XD region overwritten by k_xd.

typedef __bf16 bf16x8 __attribute__((ext_vector_type(8)));
typedef float f32x4 __attribute__((ext_vector_type(4)));

__device__ inline unsigned short f2bf(float f) {
    unsigned int u = __float_as_uint(f);
    unsigned int r = u + 0x7fffu + ((u >> 16) & 1u);
    return (unsigned short)(r >> 16);
}
__device__ inline float bf2f(unsigned short h) {
    return __uint_as_float(((unsigned int)h) << 16);
}

// direct global->LDS async copy, 16 B per lane (global_load_lds_dwordx4)
__device__ inline void gld16(const unsigned short* g, unsigned short* l) {
    __builtin_amdgcn_global_load_lds(
        (const __attribute__((address_space(1))) unsigned int*)g,
        (__attribute__((address_space(3))) unsigned int*)l,
        16, 0, 0);
}

// ---------------------------------------------- prep: cb -> CB panels + half-norms + zeros
__global__ void k_prep_cb(const float* __restrict__ cb, float* __restrict__ out) {
    int j = blockIdx.x, l = threadIdx.x;          // 2048 x 64 ; cols l*8..l*8+7
    unsigned short* cp = (unsigned short*)(out + OFF_CSUM) + 60;   // 128-B aligned
    const float* row = cb + (long long)j * K;
    float4 a = *(const float4*)(row + l * 8);
    float4 b = *(const float4*)(row + l * 8 + 4);
    float v[8] = {a.x, a.y, a.z, a.w, b.x, b.y, b.z, b.w};
    unsigned short h[8], lo[8];
    float s = 0.0f;
    #pragma unroll
    for (int k = 0; k < 8; ++k) {
        s += v[k] * v[k];
        h[k] = f2bf(v[k]);
        lo[k] = f2bf(v[k] - bf2f(h[k]));
    }
    const int p = l >> 2, cw = (l & 3) * 8;       // kstep, in-panel col
    const long long base = ((long long)p * NCODE + j) * 64;
    *(uint4*)&cp[base + cw]      = *(uint4*)h;
    *(uint4*)&cp[base + 32 + cw] = *(uint4*)lo;
    #pragma unroll
    for (int off = 32; off >= 1; off >>= 1) s += __shfl_down(s, off, 64);
    if (l == 0) out[S_NRM + j] = 0.5f * s;
    if (l == 1) ((int*)(out + S_CNT))[j] = 0;
    if (j == 0 && l == 2) out[OFF_LOSS] = 0.0f;
}

// ---------------------------------------------- transpose x -> X panels (full-line stores)
// Round-12 rewrite of the write phase: the old path issued 8-B uint2 stores, two per
// 128-B panel line (hi and lo from separate instructions) — partial-line scattered
// writes; transpose ran at 457 GB/s (5.7% peak), ~221 us, all pipes idle. Now 8 lanes
// cover one full line (4 hi-uint4 + 4 lo-uint4), each lane gathers 8 channel-words
// from LDS (banks 8c+k+tok span all 32 -> conflict-free; the h-duplication is a free
// broadcast) and issues ONE dwordx4 store; a wave writes 8 consecutive full lines.
__global__ void k_transpose(const float* __restrict__ x, float* __restrict__ out) {
    __shared__ unsigned int tile[64][65];
    unsigned short* xp = (unsigned short*)out;
    const int t0 = blockIdx.x * 64, c0 = blockIdx.y * 64, n = blockIdx.z;
    const int tid = threadIdx.x;
    #pragma unroll
    for (int i = 0; i < 4; ++i) {
        int s = tid + 256 * i;
        int cl = s >> 4, tq = (s & 15) * 4;
        float4 v = *(const float4*)(x + ((long long)(n * C_ + c0 + cl)) * T_ + t0 + tq);
        float vv[4] = {v.x, v.y, v.z, v.w};
        #pragma unroll
        for (int k = 0; k < 4; ++k) {
            unsigned short h = f2bf(vv[k]);
            unsigned short lo = f2bf(vv[k] - bf2f(h));
            tile[cl][tq + k] = ((unsigned int)h << 16) | lo;
        }
    }
    __syncthreads();
    #pragma unroll
    for (int i = 0; i < 4; ++i) {
        int r = tid + 256 * i;             // [0,1024)
        int line = r >> 3;                 // [0,128): 64 toks x 2 local panels
        int tr  = line & 63;
        int pl  = line >> 6;               // local panel 0/1
        int c8  = r & 7;                   // uint4 slot within the 128-B line
        int h   = c8 >> 2;                 // 0: hi half, 1: lo half
        int c   = c8 & 3;                  // chunk of 8 channels
        int chb = pl * 32 + c * 8;         // channel base within this 64-chan block
        unsigned short v8[8];
        #pragma unroll
        for (int k = 0; k < 8; ++k) {
            unsigned int u = tile[chb + k][tr];
            v8[k] = h ? (unsigned short)(u & 0xffff) : (unsigned short)(u >> 16);
        }
        long long tok = (long long)n * T_ + t0 + tr;
        long long base = ((long long)((c0 >> 5) + pl) * NTOK + tok) * 64 + c8 * 8;
        *(uint4*)&xp[base] = *(uint4*)v8;
    }
}

// ---------------------------------------------- MFMA argmin: 128 tok x 512 codes per block
// grid 1024 (bijective XCD swizzle). 4 waves; wave tile 64x128: moff=(w>>1)*64,
// noff=(w&1)*128. jt in {0,1} covers 256 codes each. Partial group g = jn*2 + (w&1).
// Round-8 verified configuration (180 us, MfmaUtil 51.5, WRITE 2 MB): A+B staged via
// gld16 w16 panels, XOR involution, 2 barriers/step, 64x128 wave tile (LDS frag reads
// 256 B/MFMA), __launch_bounds__(256,2) -> no spill. R9 (counted vmcnt), R10 (full
// dbuf 32x128), R11 (jn-merge) all failed to beat this — restored exactly.
__global__ __launch_bounds__(256, 2)
void k_argmin(const float* __restrict__ out_ro, float* __restrict__ out) {
    extern __shared__ unsigned short sm[];
    unsigned short* As = sm;            // [128 rows][128 B] = 16 KB
    unsigned short* Bs = sm + 8192;     // [256 rows][128 B] = 32 KB
    const unsigned short* xp = (const unsigned short*)out_ro;
    const unsigned short* cp = (const unsigned short*)(out_ro + OFF_CSUM) + 60;
    const float* nrm = out_ro + S_NRM;

    const int tid = threadIdx.x;
    const int bid = blockIdx.x;
    const int sw  = (bid & 7) * 128 + (bid >> 3);  // bijective (1024 % 8 == 0)
    const int jn  = sw >> 8;                        // code group (512)
    const int it  = sw & 255;                       // token tile (128)
    const int w = tid >> 6, L = tid & 63;
    const int quad = L >> 4, l16 = L & 15;
    const int moff = (w >> 1) * 64, noff = (w & 1) * 128;

    // staging: dest chunk linear (sA + i*2048); source row rA + i*32 with i-independent
    // chunk involution ku8; fragment read phys chunk = quad ^ (row&7), lo = hi ^ 32.
    const int sA = tid * 8;
    const int rA = tid >> 3;
    const int ku8 = ((tid & 7) ^ (rA & 7)) * 8;
    const int fhi = (quad ^ (l16 & 7)) << 3;

    float bd[4][4];
    int   bj[4][4];
    #pragma unroll
    for (int mt = 0; mt < 4; ++mt)
        #pragma unroll
        for (int r = 0; r < 4; ++r) { bd[mt][r] = 3.4e38f; bj[mt][r] = 0; }

    for (int jt = 0; jt < 2; ++jt) {
        const int jbase = jn * 512 + jt * 256;
        f32x4 acc[4][8];
        #pragma unroll
        for (int mt = 0; mt < 4; ++mt)
            #pragma unroll
            for (int nt = 0; nt < 8; ++nt) acc[mt][nt] = (f32x4)(0.0f);

        for (int p = 0; p < 16; ++p) {                 // kc = p*32
            __syncthreads();
            const long long ab = ((long long)p * NTOK + it * 128 + rA) * 64 + ku8;
            const long long bb = ((long long)p * NCODE + jbase + rA) * 64 + ku8;
            #pragma unroll
            for (int i = 0; i < 4; ++i)
                gld16(xp + ab + i * 2048, As + sA + i * 2048);
            #pragma unroll
            for (int i = 0; i < 8; ++i)
                gld16(cp + bb + i * 2048, Bs + sA + i * 2048);
            __syncthreads();   // drains vmcnt before any wave reads the tiles
            bf16x8 ah[4], al[4];
            #pragma unroll
            for (int mt = 0; mt < 4; ++mt) {
                int oa = (moff + mt * 16 + l16) * 64 + fhi;
                ah[mt] = *(const bf16x8*)&As[oa];
                al[mt] = *(const bf16x8*)&As[oa ^ 32];
            }
            #pragma unroll
            for (int nt = 0; nt < 8; ++nt) {
                int ob = (noff + nt * 16 + l16) * 64 + fhi;
                bf16x8 bh = *(const bf16x8*)&Bs[ob];
                bf16x8 bl = *(const bf16x8*)&Bs[ob ^ 32];
                #pragma unroll
                for (int mt = 0; mt < 4; ++mt)
                    acc[mt][nt] = __builtin_amdgcn_mfma_f32_16x16x32_bf16(ah[mt], bh, acc[mt][nt], 0, 0, 0);
                #pragma unroll
                for (int mt = 0; mt < 4; ++mt)
                    acc[mt][nt] = __builtin_amdgcn_mfma_f32_16x16x32_bf16(al[mt], bh, acc[mt][nt], 0, 0, 0);
                #pragma unroll
                for (int mt = 0; mt < 4; ++mt)
                    acc[mt][nt] = __builtin_amdgcn_mfma_f32_16x16x32_bf16(ah[mt], bl, acc[mt][nt], 0, 0, 0);
                __builtin_amdgcn_sched_barrier(0);     // pin bh/bl live range (reg cap)
            }
        }
        // epilogue: fold this 128x256 tile into running per-token best
        #pragma unroll
        for (int nt = 0; nt < 8; ++nt) {
            int n = jbase + noff + nt * 16 + l16;
            float nv = nrm[n];
            #pragma unroll
            for (int mt = 0; mt < 4; ++mt)
                #pragma unroll
                for (int r = 0; r < 4; ++r) {
                    float d = nv - acc[mt][nt][r];
                    if (d < bd[mt][r]) { bd[mt][r] = d; bj[mt][r] = n; }
                }
        }
    }

    // cross-lane reduce over the 16 lanes of each quad (xor masks 1,2,4,8)
    #pragma unroll
    for (int off = 1; off < 16; off <<= 1) {
        #pragma unroll
        for (int mt = 0; mt < 4; ++mt)
            #pragma unroll
            for (int r = 0; r < 4; ++r) {
                float od = __shfl_xor(bd[mt][r], off, 64);
                int   oj = __shfl_xor(bj[mt][r], off, 64);
                if (od < bd[mt][r] || (od == bd[mt][r] && oj < bj[mt][r])) {
                    bd[mt][r] = od; bj[mt][r] = oj;
                }
            }
    }
    if (l16 == 0) {
        int g = jn * 2 + (w & 1);
        float* pbd = out + S_PBD + (long long)g * NTOK;
        int*   pbj = (int*)(out + S_PBJ) + (long long)g * NTOK;
        #pragma unroll
        for (int mt = 0; mt < 4; ++mt)
            #pragma unroll
            for (int r = 0; r < 4; ++r) {
                int tok = it * 128 + moff + mt * 16 + quad * 4 + r;
                pbd[tok] = bd[mt][r];
                pbj[tok] = bj[mt][r];
            }
    }
}

// ---------------------------------------------- merge 8 partials -> idx (+ fused histogram)
__global__ void k_merge(const float* __restrict__ out_ro, int* __restrict__ idx,
                        int* __restrict__ cnt) {
    int t = blockIdx.x * 256 + threadIdx.x;
    const float* pbd = out_ro + S_PBD;
    const int*   pbj = (const int*)(out_ro + S_PBJ);
    float bd = 3.4e38f; int bj = 0;
    #pragma unroll
    for (int g = 0; g < 8; ++g) {
        float d = pbd[(long long)g * NTOK + t];
        int   j = pbj[(long long)g * NTOK + t];
        if (d < bd || (d == bd && j < bj)) { bd = d; bj = j; }
    }
    idx[t] = bj;
    atomicAdd(&cnt[bj], 1);
}

__global__ void k_scan(const int* __restrict__ cnt, int* __restrict__ base,
                       int* __restrict__ cursor, const float* __restrict__ code_count,
                       float* __restrict__ out) {
    __shared__ int ps[256];
    __shared__ float hs[256];
    int tid = threadIdx.x;
    int local[8]; int s = 0;
    #pragma unroll
    for (int q = 0; q < 8; ++q) { local[q] = cnt[tid * 8 + q]; s += local[q]; }
    ps[tid] = s; __syncthreads();
    for (int st = 1; st < 256; st <<= 1) {
        int v = (tid >= st) ? ps[tid - st] : 0;
        __syncthreads();
        ps[tid] += v;
        __syncthreads();
    }
    int b = ps[tid] - s;
    float h = 0.0f;
    #pragma unroll
    for (int q = 0; q < 8; ++q) {
        int j = tid * 8 + q;
        base[j] = b; cursor[j] = b; b += local[q];
        float p = (float)local[q] * (1.0f / 32768.0f);
        h += p * logf(p + 1e-7f);
        out[OFF_CCNT + j] = MUF * code_count[j] + OMM * (float)local[q];
    }
    hs[tid] = h; __syncthreads();
    for (int st = 128; st > 0; st >>= 1) {
        if (tid < st) hs[tid] += hs[tid + st];
        __syncthreads();
    }
    if (tid == 0) out[OFF_PERP] = expf(-hs[0]);
}

__global__ void k_place(const int* __restrict__ idx, int* __restrict__ cursor,
                        int* __restrict__ toklist) {
    int t = blockIdx.x * 256 + threadIdx.x;
    int pos = atomicAdd(&cursor[idx[t]], 1);
    toklist[pos] = t;
}

// ---------------------------------------------- segmented chunk scatter: raw new_code_sum
// 2048 blocks x 64 threads; block c handles sorted-token positions [c*16, c*16+16).
// Serial length is a fixed 16 regardless of per-code count skew. Flush is wave-uniform.
// Reads token rows from the X panels: lane l covers cols l*8..l*8+7 -> panel l>>2.
__global__ void k_chunksum(const int* __restrict__ toklist, const int* __restrict__ idx,
                           float* __restrict__ out) {
    const int c = blockIdx.x;
    const int l = threadIdx.x;
    const unsigned short* xp = (const unsigned short*)out;
    float* csum = out + OFF_CSUM;
    const int p0 = c * 16;
    const int pp = l >> 2, cw = (l & 3) * 8;
    float acc[8];
    #pragma unroll
    for (int q = 0; q < 8; ++q) acc[q] = 0.0f;
    int jcur = idx[toklist[p0]];
    #pragma unroll
    for (int i = 0; i < 16; ++i) {
        int tok = toklist[p0 + i];
        int j = idx[tok];
        if (j != jcur) {                                  // uniform across the wave
            #pragma unroll
            for (int q = 0; q < 8; ++q) {
                atomicAdd(&csum[(long long)jcur * C_ + l * 8 + q], acc[q]);
                acc[q] = 0.0f;
            }
            jcur = j;
        }
        long long base = ((long long)pp * NTOK + tok) * 64;
        uint4 hv = *(const uint4*)&xp[base + cw];
        uint4 lv = *(const uint4*)&xp[base + 32 + cw];
        unsigned int hu[4] = {hv.x, hv.y, hv.z, hv.w};
        unsigned int lu[4] = {lv.x, lv.y, lv.z, lv.w};
        #pragma unroll
        for (int q = 0; q < 4; ++q) {
            acc[q * 2 + 0] += bf2f((unsigned short)(hu[q] & 0xffff)) + bf2f((unsigned short)(lu[q] & 0xffff));
            acc[q * 2 + 1] += bf2f((unsigned short)(hu[q] >> 16))    + bf2f((unsigned short)(lu[q] >> 16));
        }
    }
    #pragma unroll
    for (int q = 0; q < 8; ++q)
        atomicAdd(&csum[(long long)jcur * C_ + l * 8 + q], acc[q]);
}

// ---------------------------------------------- x_d_out + commit loss (overwrites X panels)
__global__ void k_xd(const float* __restrict__ x, const float* __restrict__ cb,
                     const int* __restrict__ idx, float* __restrict__ out) {
    const int t = blockIdx.x * 256 + threadIdx.x;  // grid (4,4,32)
    const int c0 = blockIdx.y * 128;
    const int n = blockIdx.z;
    const int j = idx[n * T_ + t];
    const float4* cr = (const float4*)(cb + (long long)j * C_ + c0);
    const long long base = (long long)n * C_ * T_ + t;
    float ls = 0.0f;
    for (int c4 = 0; c4 < 32; ++c4) {
        float4 cv = cr[c4];
        float cvv[4] = {cv.x, cv.y, cv.z, cv.w};
        #pragma unroll
        for (int k = 0; k < 4; ++k) {
            int ci = c4 * 4 + k;
            float xv = x[base + (long long)(c0 + ci) * T_];
            float dv = cvv[k] - xv;
            out[OFF_XD + base + (long long)(c0 + ci) * T_] = xv + dv;
            ls += dv * dv;
        }
    }
    #pragma unroll
    for (int off = 32; off >= 1; off >>= 1) ls += __shfl_down(ls, off, 64);
    __shared__ float red[4];
    if ((threadIdx.x & 63) == 0) red[threadIdx.x >> 6] = ls;
    __syncthreads();
    if (threadIdx.x == 0) atomicAdd(&out[OFF_LOSS], red[0] + red[1] + red[2] + red[3]);
}

// ---------------------------------------------- codebook update/reset + CSUM EMA finalize + loss scale
__global__ void k_update_cb(const float* __restrict__ x, const float* __restrict__ code_sum,
                            float* __restrict__ out) {
    int e = blockIdx.x * 256 + threadIdx.x;   // 4096 blocks
    int j = e >> 9, c = e & 511;
    float cema = out[OFF_CCNT + j];
    float se = MUF * code_sum[e] + OMM * out[OFF_CSUM + e];   // raw acc -> EMA
    out[OFF_CSUM + e] = se;
    float val;
    if (cema >= 1.0f) val = se / fmaxf(cema, 1e-10f);
    else val = x[(long long)(j >> 10) * C_ * T_ + (long long)c * T_ + (j & 1023)];
    out[OFF_CB + e] = val;
    if (e == 0) out[OFF_LOSS] *= (1.0f / 16777216.0f);
}

// ---------------------------------------------- launch
extern "C" void kernel_launch(void* const* d_in, const int* in_sizes, int n_in,
                              void* d_out, int out_size, void* d_ws, size_t ws_size,
                              hipStream_t stream) {
    const float* x          = (const float*)d_in[0];
    const float* codebook   = (const float*)d_in[1];
    const float* code_sum   = (const float*)d_in[2];
    const float* code_count = (const float*)d_in[3];
    float* out = (float*)d_out;
    int*   idx     = (int*)(out + S_IDX);
    int*   cnt     = (int*)(out + S_CNT);
    int*   base    = (int*)(out + S_BASE);
    int*   cursor  = (int*)(out + S_CUR);
    int*   toklist = (int*)(out + S_TOK);

    constexpr int SMEM_ARGMIN = 49152;   // A 16 KB + B 32 KB; 2 blocks/CU
    hipFuncSetAttribute((const void*)k_argmin,
                        hipFuncAttributeMaxDynamicSharedMemorySize, SMEM_ARGMIN);

    k_prep_cb  <<<NCODE, 64, 0, stream>>>(codebook, out);
    dim3 gt(16, 8, 32);
    k_transpose<<<gt, 256, 0, stream>>>(x, out);
    k_argmin   <<<1024, 256, SMEM_ARGMIN, stream>>>(out, out);
    k_merge    <<<128, 256, 0, stream>>>(out, idx, cnt);
    k_scan     <<<1, 256, 0, stream>>>(cnt, base, cursor, code_count, out);
    k_place    <<<128, 256, 0, stream>>>(idx, cursor, toklist);
    hipMemsetAsync(out + OFF_CSUM, 0, (size_t)NCODE * C_ * sizeof(float), stream);
    k_chunksum <<<2048, 64, 0, stream>>>(toklist, idx, out);
    dim3 gx(4, 4, 32);
    k_xd       <<<gx, 256, 0, stream>>>(x, codebook, idx, out);
    k_update_cb<<<4096, 256, 0, stream>>>(x, code_sum, out);
}